// Round 4
// baseline (1586.501 us; speedup 1.0000x reference)
//
#include <hip/hip_runtime.h>
#include <cstdint>
#include <cstddef>

// LSTMClassifier R4: FUSED two-layer recurrence in one kernel.
// 36 streams x 4 WGs (64 h-cols each), 3 weight sets register-resident
// (Whh1, Wih2, Whh2 = 384 VGPRs/lane of bf16 MFMA B-fragments). Per-step h
// exchange between the 4 siblings via LL packets (8B relaxed agent atomics:
// {2x bf16, tag}, self-validating, no fences — R3 proved ~OK). Fusion removes
// the sequential layer1->layer2 kernel chain and the h1_all global archive;
// h2(t-1) RTT hides behind layer1 compute, only h1(t) RTT partially exposed.
// Register economy: per-ks A-frag loads (8 live regs), 2-phase poll (16 regs).

constexpr int kN = 36, kH = 256, kG = 1024, kB = 32, kT = 128, kSpec = 6, kOut = 30;
constexpr int kHP = 264; // LDS row stride (ushort): 528B rows, 16B-aligned

typedef __bf16 bf16;
typedef __bf16 bf16x8 __attribute__((ext_vector_type(8)));
typedef float f32x4 __attribute__((ext_vector_type(4)));
typedef unsigned long long u64;

__device__ __forceinline__ float sigm(float v) { return 1.f / (1.f + __expf(-v)); }
__device__ __forceinline__ float tanh_f(float v) {
  v = fminf(15.f, fmaxf(-15.f, v));
  float e = __expf(2.f * v);
  return (e - 1.f) / (e + 1.f);
}
__device__ __forceinline__ unsigned short f2bf(float f) {
  bf16 b = (bf16)f;
  return __builtin_bit_cast(unsigned short, b);
}

// ---- convert + permute weights fp32 -> bf16 MFMA B-fragment order ----
// packed[n][nt][ks][lane]: gate col g = nt*16 + (lane&15), k = ks*32 + (lane>>4)*8 + r.
__global__ __launch_bounds__(256) void k_convert(
    const float* __restrict__ wa, const float* __restrict__ wb, const float* __restrict__ wc,
    bf16* __restrict__ oa, bf16* __restrict__ ob, bf16* __restrict__ oc)
{
  const size_t total = (size_t)kN * 64 * 8 * 64;
  size_t gid = (size_t)blockIdx.x * 256 + threadIdx.x;
  if (gid >= total) return;
  const int lane = (int)(gid & 63);
  const int ks = (int)((gid >> 6) & 7);
  const int nt = (int)((gid >> 9) & 63);
  const int n = (int)(gid >> 15);
  const int g = nt * 16 + (lane & 15);
  const int k = ks * 32 + (lane >> 4) * 8;
  const size_t so = ((size_t)n * kG + g) * kH + k;

  const float4 a0 = *(const float4*)(wa + so), a1 = *(const float4*)(wa + so + 4);
  const float4 b0 = *(const float4*)(wb + so), b1 = *(const float4*)(wb + so + 4);
  const float4 c0 = *(const float4*)(wc + so), c1 = *(const float4*)(wc + so + 4);
  bf16x8 va, vb, vc;
  va[0]=(bf16)a0.x; va[1]=(bf16)a0.y; va[2]=(bf16)a0.z; va[3]=(bf16)a0.w;
  va[4]=(bf16)a1.x; va[5]=(bf16)a1.y; va[6]=(bf16)a1.z; va[7]=(bf16)a1.w;
  vb[0]=(bf16)b0.x; vb[1]=(bf16)b0.y; vb[2]=(bf16)b0.z; vb[3]=(bf16)b0.w;
  vb[4]=(bf16)b1.x; vb[5]=(bf16)b1.y; vb[6]=(bf16)b1.z; vb[7]=(bf16)b1.w;
  vc[0]=(bf16)c0.x; vc[1]=(bf16)c0.y; vc[2]=(bf16)c0.z; vc[3]=(bf16)c0.w;
  vc[4]=(bf16)c1.x; vc[5]=(bf16)c1.y; vc[6]=(bf16)c1.z; vc[7]=(bf16)c1.w;
  ((bf16x8*)oa)[gid] = va;
  ((bf16x8*)ob)[gid] = vb;
  ((bf16x8*)oc)[gid] = vc;
}

// Poll one step's 4096 packets in two 8-row phases (16 poll regs, not 32).
// Thread owns rows j/j+16 at col=tid. Self-validating via tag; no fences.
__device__ __forceinline__ void poll_stage(const u64* __restrict__ base, unsigned want,
                                           int tid, unsigned short (*hs)[kHP])
{
#pragma unroll
  for (int hf = 0; hf < 2; ++hf) {
    u64 v[8];
    unsigned got = 0;
#pragma unroll
    for (int j = 0; j < 8; ++j)
      v[j] = __hip_atomic_load(base + (size_t)(hf * 8 + j) * 256 + tid,
                               __ATOMIC_RELAXED, __HIP_MEMORY_SCOPE_AGENT);
    while (true) {
#pragma unroll
      for (int j = 0; j < 8; ++j) {
        if (!(got & (1u << j)) && (unsigned)(v[j] >> 32) == want) {
          got |= 1u << j;
          unsigned d = (unsigned)v[j];
          hs[hf * 8 + j][tid] = (unsigned short)(d & 0xFFFFu);
          hs[hf * 8 + j + 16][tid] = (unsigned short)(d >> 16);
        }
      }
      if (got == 0xFFu) break;
      __builtin_amdgcn_s_sleep(1);
#pragma unroll
      for (int j = 0; j < 8; ++j)
        if (!(got & (1u << j)))
          v[j] = __hip_atomic_load(base + (size_t)(hf * 8 + j) * 256 + tid,
                                   __ATOMIC_RELAXED, __HIP_MEMORY_SCOPE_AGENT);
    }
  }
}

// MFMA over staged h (LDS): per-ks A loads keep only 8 A-regs live.
__device__ __forceinline__ void mfma_from_lds(const unsigned short (*hs)[kHP],
                                              int l15, int l4,
                                              const bf16x8 (&W)[4][8], f32x4 (&acc)[2][4])
{
#pragma unroll
  for (int ks = 0; ks < 8; ++ks) {
    bf16x8 A0 = *(const bf16x8*)&hs[l15][ks * 32 + l4 * 8];
    bf16x8 A1 = *(const bf16x8*)&hs[16 + l15][ks * 32 + l4 * 8];
#pragma unroll
    for (int gt = 0; gt < 4; ++gt) {
      acc[0][gt] = __builtin_amdgcn_mfma_f32_16x16x32_bf16(A0, W[gt][ks], acc[0][gt], 0, 0, 0);
      acc[1][gt] = __builtin_amdgcn_mfma_f32_16x16x32_bf16(A1, W[gt][ks], acc[1][gt], 0, 0, 0);
    }
  }
}

__device__ __forceinline__ void cell_update(const f32x4 (&acc)[2][4],
                                            float (&cst)[2][4], float (&hv)[2][4])
{
#pragma unroll
  for (int mt = 0; mt < 2; ++mt)
#pragma unroll
    for (int r = 0; r < 4; ++r) {
      float cc = sigm(acc[mt][1][r]) * cst[mt][r]
               + sigm(acc[mt][0][r]) * tanh_f(acc[mt][2][r]);
      cst[mt][r] = cc;
      hv[mt][r] = sigm(acc[mt][3][r]) * tanh_f(cc);
    }
}

__device__ __forceinline__ void publish(u64* __restrict__ pub, int l4, int col,
                                        unsigned tag, const float (&hv)[2][4])
{
#pragma unroll
  for (int r = 0; r < 4; ++r) {
    unsigned lo = f2bf(hv[0][r]), hi = f2bf(hv[1][r]);
    u64 pkt = ((u64)tag << 32) | ((u64)hi << 16) | lo;
    __hip_atomic_store(pub + (size_t)(l4 * 4 + r) * 256 + col, pkt,
                       __ATOMIC_RELAXED, __HIP_MEMORY_SCOPE_AGENT);
  }
}

// ---- fused 2-layer recurrence: blk = q*64+n (siblings share XCD under %8) ----
__global__ __launch_bounds__(256) __attribute__((amdgpu_waves_per_eu(1, 1)))
void k_lstm(
    const float* __restrict__ x, const float* __restrict__ Wih1,
    const float* __restrict__ bih1, const float* __restrict__ bhh1,
    const float* __restrict__ bih2, const float* __restrict__ bhh2,
    const bf16* __restrict__ pk1, const bf16* __restrict__ pk2i,
    const bf16* __restrict__ pk2h, float* __restrict__ h2_final,
    u64* __restrict__ pkh1, u64* __restrict__ pkh2)
{
  const int blk = blockIdx.x;
  const int n = blk & 63, q = blk >> 6;
  if (n >= kN) return;
  const int tid = threadIdx.x, wv = tid >> 6, lane = tid & 63;
  const int l15 = lane & 15, l4 = lane >> 4;
  const int col = q * 64 + wv * 16 + l15;

  __shared__ alignas(16) unsigned short hs1[kB][kHP];
  __shared__ alignas(16) unsigned short hs2[kB][kHP];
  __shared__ float xsh[kT][kB];
  for (int i = tid; i < kB * kT; i += 256) {
    int b = i >> 7, t = i & (kT - 1);
    xsh[t][b] = x[((size_t)b * kT + t) * kN + n];
  }

  // three register-resident weight sets (B-fragments); nt(gt) = gt*16 + q*4 + wv
  bf16x8 Wh1[4][8], Wi2[4][8], Wh2[4][8];
  {
    const bf16x8* b1 = (const bf16x8*)pk1 + (size_t)n * 32768;
    const bf16x8* b2 = (const bf16x8*)pk2i + (size_t)n * 32768;
    const bf16x8* b3 = (const bf16x8*)pk2h + (size_t)n * 32768;
#pragma unroll
    for (int gt = 0; gt < 4; ++gt)
#pragma unroll
      for (int ks = 0; ks < 8; ++ks) {
        size_t o = (size_t)(gt * 16 + q * 4 + wv) * 512 + ks * 64 + lane;
        Wh1[gt][ks] = b1[o];
        Wi2[gt][ks] = b2[o];
        Wh2[gt][ks] = b3[o];
      }
  }
  float wih[4], bg1[4], bg2[4];
#pragma unroll
  for (int gt = 0; gt < 4; ++gt) {
    int g = gt * 256 + col;
    wih[gt] = Wih1[n * kG + g];
    bg1[gt] = bih1[n * kG + g] + bhh1[n * kG + g];
    bg2[gt] = bih2[n * kG + g] + bhh2[n * kG + g];
  }
  float cst1[2][4], cst2[2][4], hv1[2][4], hv2[2][4];
#pragma unroll
  for (int mt = 0; mt < 2; ++mt)
#pragma unroll
    for (int r = 0; r < 4; ++r) { cst1[mt][r] = 0.f; cst2[mt][r] = 0.f; }

  u64* pb1 = pkh1 + (size_t)n * 8192; // 2 parity slots x 4096 packets
  u64* pb2 = pkh2 + (size_t)n * 8192;
  __syncthreads();

#pragma unroll 1
  for (int t = 0; t < kT; ++t) {
    f32x4 acc[2][4];
    // ---- layer 1: gates = x_t*Wih1 + bg1 + Whh1*h1(t-1) ----
#pragma unroll
    for (int mt = 0; mt < 2; ++mt)
#pragma unroll
      for (int gt = 0; gt < 4; ++gt)
#pragma unroll
        for (int r = 0; r < 4; ++r)
          acc[mt][gt][r] = xsh[t][mt * 16 + l4 * 4 + r] * wih[gt] + bg1[gt];
    if (t > 0) mfma_from_lds(hs1, l15, l4, Wh1, acc); // hs1 = h1(t-1)
    cell_update(acc, cst1, hv1);
    publish(pb1 + (size_t)(t & 1) * 4096, l4, col, (unsigned)(t + 1), hv1); // h1(t) in flight

    // ---- layer 2 part A: bg2 + Whh2*h2(t-1), hides h1 RTT ----
#pragma unroll
    for (int mt = 0; mt < 2; ++mt)
#pragma unroll
      for (int gt = 0; gt < 4; ++gt)
#pragma unroll
        for (int r = 0; r < 4; ++r) acc[mt][gt][r] = bg2[gt];
    if (t > 0) {
      __syncthreads(); // all waves done reading hs1(h1(t-1)) & hs2(h2(t-2))
      poll_stage(pb2 + (size_t)((t - 1) & 1) * 4096, (unsigned)t, tid, hs2); // h2(t-1), ~arrived
      __syncthreads();
      mfma_from_lds(hs2, l15, l4, Wh2, acc);
    }

    // ---- layer 2 part B: + Wih2*h1(t) ----
    __syncthreads(); // hs1 readers (this iter's layer1 / prev Wi2) done before poll writes
    poll_stage(pb1 + (size_t)(t & 1) * 4096, (unsigned)(t + 1), tid, hs1); // h1(t)
    __syncthreads();
    mfma_from_lds(hs1, l15, l4, Wi2, acc); // hs1 reused next iter for Whh1
    cell_update(acc, cst2, hv2);
    publish(pb2 + (size_t)(t & 1) * 4096, l4, col, (unsigned)(t + 1), hv2); // h2(t) in flight

    if (t == kT - 1) {
#pragma unroll
      for (int mt = 0; mt < 2; ++mt)
#pragma unroll
        for (int r = 0; r < 4; ++r)
          h2_final[((size_t)n * kB + (mt * 16 + l4 * 4 + r)) * kH + col] = hv2[mt][r];
    }
  }
}

// ---- head ----
__global__ __launch_bounds__(256) void k_head1(
    const float* __restrict__ spec, const float* __restrict__ Wspec,
    const float* __restrict__ bspec, const float* __restrict__ Wp1,
    const float* __restrict__ h2f, float* __restrict__ partial)
{
  const int kc = blockIdx.x;
  const int b = blockIdx.y;
  const int o = threadIdx.x;
  __shared__ float fs[kH];
  if (kc < kN) {
    fs[o] = h2f[((size_t)kc * kB + b) * kH + o];
  } else {
    float v = bspec[o];
#pragma unroll
    for (int s = 0; s < kSpec; ++s) v += spec[b * kSpec + s] * Wspec[s * kH + o];
    fs[o] = v;
  }
  __syncthreads();
  const float* __restrict__ wp = Wp1 + (size_t)kc * 256 * kH + o;
  float a = 0.f;
#pragma unroll 8
  for (int i = 0; i < 256; ++i) a += fs[i] * wp[(size_t)i * kH];
  partial[((size_t)kc * kB + b) * kH + o] = a;
}

__global__ __launch_bounds__(256) void k_head2(
    const float* __restrict__ bp1, const float* __restrict__ Wp2,
    const float* __restrict__ bp2, const float* __restrict__ partial,
    float* __restrict__ out)
{
  const int b = blockIdx.x;
  const int o = threadIdx.x;
  __shared__ float hid[kH];
  float a = bp1[o];
#pragma unroll
  for (int kc = 0; kc < kN + 1; ++kc) a += partial[((size_t)kc * kB + b) * kH + o];
  hid[o] = fmaxf(a, 0.f);
  __syncthreads();
  if (o < kOut) {
    float r = bp2[o];
#pragma unroll 8
    for (int h = 0; h < kH; ++h) r += hid[h] * Wp2[h * kOut + o];
    out[b * kOut + o] = r;
  }
}

extern "C" void kernel_launch(void* const* d_in, const int* in_sizes, int n_in,
                              void* d_out, int out_size, void* d_ws, size_t ws_size,
                              hipStream_t stream) {
  const float* x = (const float*)d_in[0];
  const float* spec = (const float*)d_in[1];
  const float* Wih1 = (const float*)d_in[2];
  const float* Whh1 = (const float*)d_in[3];
  const float* bih1 = (const float*)d_in[4];
  const float* bhh1 = (const float*)d_in[5];
  const float* Wih2 = (const float*)d_in[6];
  const float* Whh2 = (const float*)d_in[7];
  const float* bih2 = (const float*)d_in[8];
  const float* bhh2 = (const float*)d_in[9];
  const float* Wspec = (const float*)d_in[10];
  const float* bspec = (const float*)d_in[11];
  const float* Wp1 = (const float*)d_in[12];
  const float* bp1 = (const float*)d_in[13];
  const float* Wp2 = (const float*)d_in[14];
  const float* bp2 = (const float*)d_in[15];
  float* out = (float*)d_out;

  // ws layout (~85 MB): [pk1|pk2i|pk2h bf16 56.6M][pkh1 2.36M][pkh2 2.36M]
  //                     [h2_final f32 4.7M][partial f32 18.9M]
  // No memset needed: LL tags 1..128 never match the 0xAA poison pattern.
  const size_t WSZ = (size_t)kN * kG * kH;
  bf16* pk1 = (bf16*)d_ws;
  bf16* pk2i = pk1 + WSZ;
  bf16* pk2h = pk2i + WSZ;
  u64* pkh1 = (u64*)(pk2h + WSZ);
  u64* pkh2 = pkh1 + (size_t)kN * 2 * 4096;
  float* h2_final = (float*)(pkh2 + (size_t)kN * 2 * 4096);
  float* partial = h2_final + (size_t)kN * kB * kH;

  const size_t groups = (size_t)kN * 64 * 8 * 64;
  k_convert<<<dim3((unsigned)((groups + 255) / 256)), dim3(256), 0, stream>>>(
      Whh1, Wih2, Whh2, pk1, pk2i, pk2h);
  k_lstm<<<dim3(256), dim3(256), 0, stream>>>(
      x, Wih1, bih1, bhh1, bih2, bhh2, pk1, pk2i, pk2h, h2_final, pkh1, pkh2);
  k_head1<<<dim3(kN + 1, kB), dim3(256), 0, stream>>>(spec, Wspec, bspec, Wp1, h2_final, partial);
  k_head2<<<dim3(kB), dim3(256), 0, stream>>>(bp1, Wp2, bp2, partial, out);
}